// Round 5
// baseline (138.880 us; speedup 1.0000x reference)
//
#include <hip/hip_runtime.h>
#include <hip/hip_bf16.h>

// Problem constants
#define BB 2
#define NN 512
#define P0 16
#define P1 32
#define P2 32
#define HH 128

typedef __attribute__((ext_vector_type(8))) short bf16x8;
typedef __attribute__((ext_vector_type(4))) float f32x4;
typedef __attribute__((ext_vector_type(4))) unsigned u32x4;

__device__ __forceinline__ unsigned pkbf(float lo, float hi) {
  // Compiler-lowered packed f32->bf16 RNE; .x lands in low 16 bits.
  __hip_bfloat162 h = __float22bfloat162_rn(float2{lo, hi});
  unsigned r;
  __builtin_memcpy(&r, &h, 4);  // bit_cast rejected (non-trivially-copyable)
  return r;
}

__device__ __forceinline__ short f2b(float f) {
  // scalar f32 -> bf16 RNE (cold paths)
  unsigned u = __builtin_bit_cast(unsigned, f);
  u = (u + 0x7FFFu + ((u >> 16) & 1u)) >> 16;
  return (short)u;
}

__device__ __forceinline__ float sigm(float x) {
  return __builtin_amdgcn_rcpf(1.0f + __expf(-x));
}

__device__ __forceinline__ bf16x8 pack2(f32x4 a, f32x4 b) {
  u32x4 u;
  u[0] = pkbf(a[0], a[1]);
  u[1] = pkbf(a[2], a[3]);
  u[2] = pkbf(b[0], b[1]);
  u[3] = pkbf(b[2], b[3]);
  return __builtin_bit_cast(bf16x8, u);
}

// ---------------------------------------------------------------------------
// Arity-2: out2[b,i,j,:] = mlp(concat[x2[b,i,j,:], x1[b,i,:], x2[b,j,i,:], x1[b,j,:]])
// 128 -> 128 (sigmoid) -> 32 (sigmoid) via bf16 MFMA 16x16x32, transposed GEMMs.
// vs round 3: packed-cvt conversions (same logical placement -> same math),
// s=1 (x1[b,i]*W1 + b1) hoisted into per-block base accumulator, no explicit
// prefetch, LDS trimmed to exactly 32 KiB (per-wave wsred partial slots).
// ---------------------------------------------------------------------------
__global__ __launch_bounds__(256, 4) void k_arity2(
    const float* __restrict__ x1, const float* __restrict__ x2,
    const float* __restrict__ W1, const float* __restrict__ b1,
    const float* __restrict__ W2, const float* __restrict__ b2,
    float* __restrict__ out2, float* __restrict__ wsred) {
  __shared__ __align__(16) short lw[32 * 64 * 8];  // W1 frags: exactly 32 KiB

  const int tid = threadIdx.x;
  const int bid = blockIdx.x;       // 0..2047
  const int b  = bid >> 10;         // 0..1
  const int i  = (bid >> 1) & 511;  // 0..511
  const int jh = bid & 1;           // half of j range

  // Stage W1 fragments to LDS (pre-swizzled to MFMA fragment order).
  for (int c = tid; c < 2048; c += 256) {
    const int l = c & 63, th = (c >> 6) & 7, s = c >> 9;
    const int fm = l & 15, fb = l >> 4;
    const int h = 16 * th + fm;
    float v[8];
#pragma unroll
    for (int e = 0; e < 8; ++e) {
      const int k = 32 * s + 4 * fb + (e & 3) + 16 * (e >> 2);
      v[e] = W1[k * HH + h];
    }
    unsigned* dst = (unsigned*)&lw[c * 8];
#pragma unroll
    for (int t = 0; t < 4; ++t) dst[t] = pkbf(v[2 * t], v[2 * t + 1]);
  }

  const int lane = tid & 63;
  const int wv = tid >> 6;
  const int m = lane & 15, bq = lane >> 4;

  // W2^T fragments in registers: A2[p][h], p = 16*pt + m
  bf16x8 w2f[2][4];
#pragma unroll
  for (int pt = 0; pt < 2; ++pt) {
#pragma unroll
    for (int s = 0; s < 4; ++s) {
      const int p = 16 * pt + m;
      float v[8];
#pragma unroll
      for (int e = 0; e < 8; ++e) {
        const int h = 32 * s + 4 * bq + (e & 3) + 16 * (e >> 2);
        v[e] = W2[h * P2 + p];
      }
      u32x4 u;
#pragma unroll
      for (int t = 0; t < 4; ++t) u[t] = pkbf(v[2 * t], v[2 * t + 1]);
      w2f[pt][s] = __builtin_bit_cast(bf16x8, u);
    }
  }

  f32x4 bias2[2];
#pragma unroll
  for (int pt = 0; pt < 2; ++pt)
#pragma unroll
    for (int r = 0; r < 4; ++r) bias2[pt][r] = b2[16 * pt + 4 * bq + r];

  // x1[b,i,:] fragment (k-step s=1), constant over the block
  const float* x1bi = x1 + ((size_t)b * NN + i) * P1;
  const bf16x8 f1 = pack2(*(const f32x4*)(x1bi + 4 * bq),
                          *(const f32x4*)(x1bi + 16 + 4 * bq));

  __syncthreads();

  const bf16x8* wl = (const bf16x8*)lw;

  // Hoisted s=1 contribution: base[th] = W1[s=1]^T . f1 + b1  (per-lane frags)
  f32x4 base[8];
#pragma unroll
  for (int th = 0; th < 8; ++th) {
    f32x4 bi;
#pragma unroll
    for (int r = 0; r < 4; ++r) bi[r] = b1[16 * th + 4 * bq + r];
    base[th] = __builtin_amdgcn_mfma_f32_16x16x32_bf16(wl[(8 + th) * 64 + lane], f1, bi, 0, 0, 0);
  }

  // Fused arity-1 reduction partials over this lane's direct rows.
  // Diagonal contributes exactly 0 (max) / 1 (min), matching the reference mask.
  f32x4 pmx0 = {0.f, 0.f, 0.f, 0.f}, pmx1 = {0.f, 0.f, 0.f, 0.f};
  f32x4 pmn0 = {1.f, 1.f, 1.f, 1.f}, pmn1 = {1.f, 1.f, 1.f, 1.f};

  const int jb = jh * 256 + wv * 16 + m;

#pragma unroll
  for (int it = 0; it < 4; ++it) {
    const int j = jb + it * 64;
    const float* p0 = x2 + (((size_t)b * NN + i) * NN + j) * P2;  // x2[b,i,j,:]
    const float* p2 = x2 + (((size_t)b * NN + j) * NN + i) * P2;  // x2[b,j,i,:]
    const float* p3 = x1 + ((size_t)b * NN + j) * P1;             // x1[b,j,:]
    const f32x4 c0a = *(const f32x4*)(p0 + 4 * bq), c0b = *(const f32x4*)(p0 + 16 + 4 * bq);
    const f32x4 c2a = *(const f32x4*)(p2 + 4 * bq), c2b = *(const f32x4*)(p2 + 16 + 4 * bq);
    const f32x4 c3a = *(const f32x4*)(p3 + 4 * bq), c3b = *(const f32x4*)(p3 + 16 + 4 * bq);

    // Reduction accumulate on the direct row (raw f32, before packing)
    {
      const bool dg = (j == i);
#pragma unroll
      for (int r = 0; r < 4; ++r) {
        const float va = dg ? 0.0f : c0a[r], vb = dg ? 0.0f : c0b[r];
        const float wa = dg ? 1.0f : c0a[r], wb = dg ? 1.0f : c0b[r];
        pmx0[r] = fmaxf(pmx0[r], va); pmx1[r] = fmaxf(pmx1[r], vb);
        pmn0[r] = fminf(pmn0[r], wa); pmn1[r] = fminf(pmn1[r], wb);
      }
    }

    const bf16x8 f0 = pack2(c0a, c0b);
    const bf16x8 f2 = pack2(c2a, c2b);
    const bf16x8 f3 = pack2(c3a, c3b);

    // GEMM1: D1^T[h][j] ; acc[th] reg r holds h = 16*th + 4*bq + r, col j
    f32x4 acc[8];
#pragma unroll
    for (int th = 0; th < 8; ++th)
      acc[th] = __builtin_amdgcn_mfma_f32_16x16x32_bf16(wl[(0 + th) * 64 + lane], f0, base[th], 0, 0, 0);
#pragma unroll
    for (int th = 0; th < 8; ++th)
      acc[th] = __builtin_amdgcn_mfma_f32_16x16x32_bf16(wl[(16 + th) * 64 + lane], f2, acc[th], 0, 0, 0);
#pragma unroll
    for (int th = 0; th < 8; ++th)
      acc[th] = __builtin_amdgcn_mfma_f32_16x16x32_bf16(wl[(24 + th) * 64 + lane], f3, acc[th], 0, 0, 0);

    // GEMM2: out^T[p][j] = W2^T @ sigmoid(D1^T)
    f32x4 acc2[2];
#pragma unroll
    for (int pt = 0; pt < 2; ++pt) acc2[pt] = bias2[pt];
#pragma unroll
    for (int s = 0; s < 4; ++s) {
      float sv[8];
#pragma unroll
      for (int e = 0; e < 4; ++e) {
        sv[e]     = sigm(acc[2 * s][e]);
        sv[4 + e] = sigm(acc[2 * s + 1][e]);
      }
      u32x4 u;
#pragma unroll
      for (int t = 0; t < 4; ++t) u[t] = pkbf(sv[2 * t], sv[2 * t + 1]);
      const bf16x8 bf = __builtin_bit_cast(bf16x8, u);
#pragma unroll
      for (int pt = 0; pt < 2; ++pt)
        acc2[pt] = __builtin_amdgcn_mfma_f32_16x16x32_bf16(w2f[pt][s], bf, acc2[pt], 0, 0, 0);
    }

    // Epilogue: sigmoid + store. acc2[pt] reg r -> p = 16*pt + 4*bq + r, row j.
    float* op = out2 + (((size_t)b * NN + i) * NN + j) * P2;
#pragma unroll
    for (int pt = 0; pt < 2; ++pt) {
      f32x4 o;
#pragma unroll
      for (int r = 0; r < 4; ++r) o[r] = sigm(acc2[pt][r]);
      *(f32x4*)(op + 16 * pt + 4 * bq) = o;
    }
  }

  // Finish fused reduction: butterfly over the 16 m-lanes, then per-wave slot.
  if (wsred) {
#pragma unroll
    for (int msk = 1; msk < 16; msk <<= 1) {
#pragma unroll
      for (int r = 0; r < 4; ++r) {
        pmx0[r] = fmaxf(pmx0[r], __shfl_xor(pmx0[r], msk));
        pmx1[r] = fmaxf(pmx1[r], __shfl_xor(pmx1[r], msk));
        pmn0[r] = fminf(pmn0[r], __shfl_xor(pmn0[r], msk));
        pmn1[r] = fminf(pmn1[r], __shfl_xor(pmn1[r], msk));
      }
    }
    if (m == 0) {
      const int slot = jh * 4 + wv;
      const size_t o = (((size_t)b * NN + i) * 8 + slot) * 64;
#pragma unroll
      for (int r = 0; r < 4; ++r) {
        wsred[o + 4 * bq + r]      = pmx0[r];
        wsred[o + 16 + 4 * bq + r] = pmx1[r];
        wsred[o + 32 + 4 * bq + r] = pmn0[r];
        wsred[o + 48 + 4 * bq + r] = pmn1[r];
      }
    }
  }
}

// ---------------------------------------------------------------------------
// Arity-1 (fast): partial reductions come from wsred (8 slots); tiny MLP.
// ---------------------------------------------------------------------------
__global__ __launch_bounds__(128) void k_arity1_fast(
    const float* __restrict__ x0, const float* __restrict__ x1,
    const float* __restrict__ wsred, const float* __restrict__ W1,
    const float* __restrict__ b1, const float* __restrict__ W2,
    const float* __restrict__ b2, float* __restrict__ out1) {
  __shared__ float in1[112];
  __shared__ float hid[HH];

  const int tid = threadIdx.x;
  const int bid = blockIdx.x;  // 0..1023
  const int b = bid >> 9, i = bid & 511;
  const size_t o = ((size_t)b * NN + i) * 512;

  if (tid < 32) {
    float a = wsred[o + tid], c = wsred[o + 32 + tid];
#pragma unroll
    for (int s = 1; s < 8; ++s) {
      a = fmaxf(a, wsred[o + s * 64 + tid]);
      c = fminf(c, wsred[o + s * 64 + 32 + tid]);
    }
    in1[tid] = x1[((size_t)b * NN + i) * P1 + tid];
    in1[48 + tid] = a;
    in1[80 + tid] = c;
  } else if (tid < 48) {
    in1[tid] = x0[b * P0 + (tid - 32)];
  }
  __syncthreads();

  {
    float s = b1[tid];
    for (int k = 0; k < 112; ++k) s += in1[k] * W1[k * HH + tid];
    hid[tid] = sigm(s);
  }
  __syncthreads();

  if (tid < 32) {
    float s = b2[tid];
    for (int k = 0; k < 128; ++k) s += hid[k] * W2[k * P1 + tid];
    out1[((size_t)b * NN + i) * P1 + tid] = sigm(s);
  }
}

// ---------------------------------------------------------------------------
// Arity-1 (fallback, full x2 scan) — used only if ws is too small.
// ---------------------------------------------------------------------------
__global__ __launch_bounds__(256) void k_arity1(
    const float* __restrict__ x0, const float* __restrict__ x1,
    const float* __restrict__ x2, const float* __restrict__ W1,
    const float* __restrict__ b1, const float* __restrict__ W2,
    const float* __restrict__ b2, float* __restrict__ out1) {
  __shared__ float rmx[8][32], rmn[8][32];
  __shared__ float in1[112];
  __shared__ float hid[128];

  const int tid = threadIdx.x;
  const int bid = blockIdx.x;  // 0..1023
  const int b = bid >> 9, i = bid & 511;
  const int p = tid & 31, jg = tid >> 5;

  const float* base = x2 + (((size_t)b * NN + i) * NN) * P2;
  float mx = 0.0f, mn = 1.0f;
  for (int j = jg; j < NN; j += 8) {
    const float v = base[(size_t)j * P2 + p];
    mx = fmaxf(mx, (j == i) ? 0.0f : v);
    mn = fminf(mn, (j == i) ? 1.0f : v);
  }
  rmx[jg][p] = mx;
  rmn[jg][p] = mn;
  __syncthreads();

  if (tid < 32) {
    float a = rmx[0][tid], c = rmn[0][tid];
#pragma unroll
    for (int g = 1; g < 8; ++g) {
      a = fmaxf(a, rmx[g][tid]);
      c = fminf(c, rmn[g][tid]);
    }
    in1[tid] = x1[((size_t)b * NN + i) * P1 + tid];
    in1[48 + tid] = a;
    in1[80 + tid] = c;
  } else if (tid < 48) {
    in1[tid] = x0[b * P0 + (tid - 32)];
  }
  __syncthreads();

  if (tid < 128) {
    float s = b1[tid];
    for (int k = 0; k < 112; ++k) s += in1[k] * W1[k * HH + tid];
    hid[tid] = sigm(s);
  }
  __syncthreads();

  if (tid < 32) {
    float s = b2[tid];
    for (int k = 0; k < 128; ++k) s += hid[k] * W2[k * P1 + tid];
    out1[((size_t)b * NN + i) * P1 + tid] = sigm(s);
  }
}

// ---------------------------------------------------------------------------
// Arity-0
// ---------------------------------------------------------------------------
__global__ __launch_bounds__(256) void k_arity0(
    const float* __restrict__ x0, const float* __restrict__ x1,
    const float* __restrict__ W1, const float* __restrict__ b1,
    const float* __restrict__ W2, const float* __restrict__ b2,
    float* __restrict__ out0) {
  __shared__ float rmx[8][32], rmn[8][32];
  __shared__ float in0[80];
  __shared__ float hid[128];

  const int tid = threadIdx.x;
  const int b = blockIdx.x;  // 0..1
  const int p = tid & 31, jg = tid >> 5;

  float mx = -1e30f, mn = 1e30f;
  for (int j = jg; j < NN; j += 8) {
    const float v = x1[((size_t)b * NN + j) * P1 + p];
    mx = fmaxf(mx, v);
    mn = fminf(mn, v);
  }
  rmx[jg][p] = mx;
  rmn[jg][p] = mn;
  __syncthreads();

  if (tid < 32) {
    float a = rmx[0][tid], c = rmn[0][tid];
#pragma unroll
    for (int g = 1; g < 8; ++g) {
      a = fmaxf(a, rmx[g][tid]);
      c = fminf(c, rmn[g][tid]);
    }
    in0[16 + tid] = a;
    in0[48 + tid] = c;
  } else if (tid < 48) {
    in0[tid - 32] = x0[b * P0 + (tid - 32)];
  }
  __syncthreads();

  if (tid < 128) {
    float s = b1[tid];
    for (int k = 0; k < 80; ++k) s += in0[k] * W1[k * HH + tid];
    hid[tid] = sigm(s);
  }
  __syncthreads();

  if (tid < 16) {
    float s = b2[tid];
    for (int k = 0; k < 128; ++k) s += hid[k] * W2[k * P0 + tid];
    out0[b * P0 + tid] = sigm(s);
  }
}

extern "C" void kernel_launch(void* const* d_in, const int* in_sizes, int n_in,
                              void* d_out, int out_size, void* d_ws, size_t ws_size,
                              hipStream_t stream) {
  const float* x0   = (const float*)d_in[0];
  const float* x1   = (const float*)d_in[1];
  const float* x2   = (const float*)d_in[2];
  const float* W1_0 = (const float*)d_in[3];
  const float* b1_0 = (const float*)d_in[4];
  const float* W2_0 = (const float*)d_in[5];
  const float* b2_0 = (const float*)d_in[6];
  const float* W1_1 = (const float*)d_in[7];
  const float* b1_1 = (const float*)d_in[8];
  const float* W2_1 = (const float*)d_in[9];
  const float* b2_1 = (const float*)d_in[10];
  const float* W1_2 = (const float*)d_in[11];
  const float* b1_2 = (const float*)d_in[12];
  const float* W2_2 = (const float*)d_in[13];
  const float* b2_2 = (const float*)d_in[14];

  float* out0 = (float*)d_out;
  float* out1 = out0 + (size_t)BB * P0;
  float* out2 = out1 + (size_t)BB * NN * P1;

  const bool use_ws = ws_size >= (size_t)BB * NN * 8 * 64 * sizeof(float);  // 2 MiB
  float* wsred = use_ws ? (float*)d_ws : nullptr;

  hipLaunchKernelGGL(k_arity2, dim3(2048), dim3(256), 0, stream,
                     x1, x2, W1_2, b1_2, W2_2, b2_2, out2, wsred);
  if (use_ws) {
    hipLaunchKernelGGL(k_arity1_fast, dim3(1024), dim3(128), 0, stream,
                       x0, x1, wsred, W1_1, b1_1, W2_1, b2_1, out1);
  } else {
    hipLaunchKernelGGL(k_arity1, dim3(1024), dim3(256), 0, stream,
                       x0, x1, x2, W1_1, b1_1, W2_1, b2_1, out1);
  }
  hipLaunchKernelGGL(k_arity0, dim3(2), dim3(256), 0, stream,
                     x0, x1, W1_0, b1_0, W2_0, b2_0, out0);
}

// Round 6
// 94.683 us; speedup vs baseline: 1.4668x; 1.4668x over previous
//
#include <hip/hip_runtime.h>
#include <hip/hip_bf16.h>

// Problem constants
#define BB 2
#define NN 512
#define P0 16
#define P1 32
#define P2 32
#define HH 128

typedef __attribute__((ext_vector_type(8))) short bf16x8;
typedef __attribute__((ext_vector_type(4))) float f32x4;
typedef __attribute__((ext_vector_type(4))) unsigned u32x4;

__device__ __forceinline__ unsigned pkbf(float lo, float hi) {
  // Compiler-lowered packed f32->bf16 RNE; .x lands in low 16 bits.
  __hip_bfloat162 h = __float22bfloat162_rn(float2{lo, hi});
  unsigned r;
  __builtin_memcpy(&r, &h, 4);  // bit_cast rejected (non-trivially-copyable)
  return r;
}

__device__ __forceinline__ short f2b(float f) {
  // scalar f32 -> bf16 RNE (cold paths)
  unsigned u = __builtin_bit_cast(unsigned, f);
  u = (u + 0x7FFFu + ((u >> 16) & 1u)) >> 16;
  return (short)u;
}

__device__ __forceinline__ float sigm(float x) {
  return __builtin_amdgcn_rcpf(1.0f + __expf(-x));
}

__device__ __forceinline__ bf16x8 pack2(f32x4 a, f32x4 b) {
  u32x4 u;
  u[0] = pkbf(a[0], a[1]);
  u[1] = pkbf(a[2], a[3]);
  u[2] = pkbf(b[0], b[1]);
  u[3] = pkbf(b[2], b[3]);
  return __builtin_bit_cast(bf16x8, u);
}

// ---------------------------------------------------------------------------
// Arity-2: out2[b,i,j,:] = mlp(concat[x2[b,i,j,:], x1[b,i,:], x2[b,j,i,:], x1[b,j,:]])
// 128 -> 128 (sigmoid) -> 32 (sigmoid) via bf16 MFMA 16x16x32, transposed GEMMs.
// NOTE: plain __launch_bounds__(256). Round 5's (256,4) clamped VGPR to 64 and
// spilled ~270 MB/dispatch to scratch (WRITE_SIZE 66->239 MB) — never again.
// ---------------------------------------------------------------------------
__global__ __launch_bounds__(256) void k_arity2(
    const float* __restrict__ x1, const float* __restrict__ x2,
    const float* __restrict__ W1, const float* __restrict__ b1,
    const float* __restrict__ W2, const float* __restrict__ b2,
    float* __restrict__ out2, float* __restrict__ wsred) {
  __shared__ __align__(16) short lw[32 * 64 * 8];  // W1 frags: exactly 32 KiB

  const int tid = threadIdx.x;
  const int bid = blockIdx.x;       // 0..2047
  const int b  = bid >> 10;         // 0..1
  const int i  = (bid >> 1) & 511;  // 0..511
  const int jh = bid & 1;           // half of j range

  // Stage W1 fragments to LDS (pre-swizzled to MFMA fragment order).
  for (int c = tid; c < 2048; c += 256) {
    const int l = c & 63, th = (c >> 6) & 7, s = c >> 9;
    const int fm = l & 15, fb = l >> 4;
    const int h = 16 * th + fm;
    float v[8];
#pragma unroll
    for (int e = 0; e < 8; ++e) {
      const int k = 32 * s + 4 * fb + (e & 3) + 16 * (e >> 2);
      v[e] = W1[k * HH + h];
    }
    unsigned* dst = (unsigned*)&lw[c * 8];
#pragma unroll
    for (int t = 0; t < 4; ++t) dst[t] = pkbf(v[2 * t], v[2 * t + 1]);
  }

  const int lane = tid & 63;
  const int wv = tid >> 6;
  const int m = lane & 15, bq = lane >> 4;

  // W2^T fragments in registers: A2[p][h], p = 16*pt + m
  bf16x8 w2f[2][4];
#pragma unroll
  for (int pt = 0; pt < 2; ++pt) {
#pragma unroll
    for (int s = 0; s < 4; ++s) {
      const int p = 16 * pt + m;
      float v[8];
#pragma unroll
      for (int e = 0; e < 8; ++e) {
        const int h = 32 * s + 4 * bq + (e & 3) + 16 * (e >> 2);
        v[e] = W2[h * P2 + p];
      }
      u32x4 u;
#pragma unroll
      for (int t = 0; t < 4; ++t) u[t] = pkbf(v[2 * t], v[2 * t + 1]);
      w2f[pt][s] = __builtin_bit_cast(bf16x8, u);
    }
  }

  f32x4 bias2[2];
#pragma unroll
  for (int pt = 0; pt < 2; ++pt)
#pragma unroll
    for (int r = 0; r < 4; ++r) bias2[pt][r] = b2[16 * pt + 4 * bq + r];

  // x1[b,i,:] fragment (k-step s=1), constant over the block
  const float* x1bi = x1 + ((size_t)b * NN + i) * P1;
  const bf16x8 f1 = pack2(*(const f32x4*)(x1bi + 4 * bq),
                          *(const f32x4*)(x1bi + 16 + 4 * bq));

  __syncthreads();

  const bf16x8* wl = (const bf16x8*)lw;

  // Hoisted s=1 contribution: base[th] = W1[s=1]^T . f1 + b1  (per-lane frags)
  f32x4 base[8];
#pragma unroll
  for (int th = 0; th < 8; ++th) {
    f32x4 bi;
#pragma unroll
    for (int r = 0; r < 4; ++r) bi[r] = b1[16 * th + 4 * bq + r];
    base[th] = __builtin_amdgcn_mfma_f32_16x16x32_bf16(wl[(8 + th) * 64 + lane], f1, bi, 0, 0, 0);
  }

  // Fused arity-1 reduction partials over this lane's direct rows.
  // Diagonal contributes exactly 0 (max) / 1 (min), matching the reference mask.
  f32x4 pmx0 = {0.f, 0.f, 0.f, 0.f}, pmx1 = {0.f, 0.f, 0.f, 0.f};
  f32x4 pmn0 = {1.f, 1.f, 1.f, 1.f}, pmn1 = {1.f, 1.f, 1.f, 1.f};

  const int jb = jh * 256 + wv * 16 + m;

#pragma unroll
  for (int it = 0; it < 4; ++it) {
    const int j = jb + it * 64;
    const float* p0 = x2 + (((size_t)b * NN + i) * NN + j) * P2;  // x2[b,i,j,:]
    const float* p2 = x2 + (((size_t)b * NN + j) * NN + i) * P2;  // x2[b,j,i,:]
    const float* p3 = x1 + ((size_t)b * NN + j) * P1;             // x1[b,j,:]
    const f32x4 c0a = *(const f32x4*)(p0 + 4 * bq), c0b = *(const f32x4*)(p0 + 16 + 4 * bq);
    const f32x4 c2a = *(const f32x4*)(p2 + 4 * bq), c2b = *(const f32x4*)(p2 + 16 + 4 * bq);
    const f32x4 c3a = *(const f32x4*)(p3 + 4 * bq), c3b = *(const f32x4*)(p3 + 16 + 4 * bq);

    // Reduction accumulate on the direct row (raw f32, before packing)
    {
      const bool dg = (j == i);
#pragma unroll
      for (int r = 0; r < 4; ++r) {
        const float va = dg ? 0.0f : c0a[r], vb = dg ? 0.0f : c0b[r];
        const float wa = dg ? 1.0f : c0a[r], wb = dg ? 1.0f : c0b[r];
        pmx0[r] = fmaxf(pmx0[r], va); pmx1[r] = fmaxf(pmx1[r], vb);
        pmn0[r] = fminf(pmn0[r], wa); pmn1[r] = fminf(pmn1[r], wb);
      }
    }

    const bf16x8 f0 = pack2(c0a, c0b);
    const bf16x8 f2 = pack2(c2a, c2b);
    const bf16x8 f3 = pack2(c3a, c3b);

    // GEMM1: D1^T[h][j] ; acc[th] reg r holds h = 16*th + 4*bq + r, col j
    f32x4 acc[8];
#pragma unroll
    for (int th = 0; th < 8; ++th)
      acc[th] = __builtin_amdgcn_mfma_f32_16x16x32_bf16(wl[(0 + th) * 64 + lane], f0, base[th], 0, 0, 0);
#pragma unroll
    for (int th = 0; th < 8; ++th)
      acc[th] = __builtin_amdgcn_mfma_f32_16x16x32_bf16(wl[(16 + th) * 64 + lane], f2, acc[th], 0, 0, 0);
#pragma unroll
    for (int th = 0; th < 8; ++th)
      acc[th] = __builtin_amdgcn_mfma_f32_16x16x32_bf16(wl[(24 + th) * 64 + lane], f3, acc[th], 0, 0, 0);

    // GEMM2: out^T[p][j] = W2^T @ sigmoid(D1^T)
    f32x4 acc2[2];
#pragma unroll
    for (int pt = 0; pt < 2; ++pt) acc2[pt] = bias2[pt];
#pragma unroll
    for (int s = 0; s < 4; ++s) {
      float sv[8];
#pragma unroll
      for (int e = 0; e < 4; ++e) {
        sv[e]     = sigm(acc[2 * s][e]);
        sv[4 + e] = sigm(acc[2 * s + 1][e]);
      }
      u32x4 u;
#pragma unroll
      for (int t = 0; t < 4; ++t) u[t] = pkbf(sv[2 * t], sv[2 * t + 1]);
      const bf16x8 bf = __builtin_bit_cast(bf16x8, u);
#pragma unroll
      for (int pt = 0; pt < 2; ++pt)
        acc2[pt] = __builtin_amdgcn_mfma_f32_16x16x32_bf16(w2f[pt][s], bf, acc2[pt], 0, 0, 0);
    }

    // Epilogue: sigmoid + store. acc2[pt] reg r -> p = 16*pt + 4*bq + r, row j.
    float* op = out2 + (((size_t)b * NN + i) * NN + j) * P2;
#pragma unroll
    for (int pt = 0; pt < 2; ++pt) {
      f32x4 o;
#pragma unroll
      for (int r = 0; r < 4; ++r) o[r] = sigm(acc2[pt][r]);
      *(f32x4*)(op + 16 * pt + 4 * bq) = o;
    }
  }

  // Finish fused reduction: butterfly over the 16 m-lanes, then per-wave slot.
  if (wsred) {
#pragma unroll
    for (int msk = 1; msk < 16; msk <<= 1) {
#pragma unroll
      for (int r = 0; r < 4; ++r) {
        pmx0[r] = fmaxf(pmx0[r], __shfl_xor(pmx0[r], msk));
        pmx1[r] = fmaxf(pmx1[r], __shfl_xor(pmx1[r], msk));
        pmn0[r] = fminf(pmn0[r], __shfl_xor(pmn0[r], msk));
        pmn1[r] = fminf(pmn1[r], __shfl_xor(pmn1[r], msk));
      }
    }
    if (m == 0) {
      const int slot = jh * 4 + wv;
      const size_t o = (((size_t)b * NN + i) * 8 + slot) * 64;
#pragma unroll
      for (int r = 0; r < 4; ++r) {
        wsred[o + 4 * bq + r]      = pmx0[r];
        wsred[o + 16 + 4 * bq + r] = pmx1[r];
        wsred[o + 32 + 4 * bq + r] = pmn0[r];
        wsred[o + 48 + 4 * bq + r] = pmn1[r];
      }
    }
  }
}

// ---------------------------------------------------------------------------
// Arity-1 (fast): partial reductions come from wsred (8 slots); tiny MLP.
// ---------------------------------------------------------------------------
__global__ __launch_bounds__(128) void k_arity1_fast(
    const float* __restrict__ x0, const float* __restrict__ x1,
    const float* __restrict__ wsred, const float* __restrict__ W1,
    const float* __restrict__ b1, const float* __restrict__ W2,
    const float* __restrict__ b2, float* __restrict__ out1) {
  __shared__ float in1[112];
  __shared__ float hid[HH];

  const int tid = threadIdx.x;
  const int bid = blockIdx.x;  // 0..1023
  const int b = bid >> 9, i = bid & 511;
  const size_t o = ((size_t)b * NN + i) * 512;

  if (tid < 32) {
    float a = wsred[o + tid], c = wsred[o + 32 + tid];
#pragma unroll
    for (int s = 1; s < 8; ++s) {
      a = fmaxf(a, wsred[o + s * 64 + tid]);
      c = fminf(c, wsred[o + s * 64 + 32 + tid]);
    }
    in1[tid] = x1[((size_t)b * NN + i) * P1 + tid];
    in1[48 + tid] = a;
    in1[80 + tid] = c;
  } else if (tid < 48) {
    in1[tid] = x0[b * P0 + (tid - 32)];
  }
  __syncthreads();

  {
    float s = b1[tid];
    for (int k = 0; k < 112; ++k) s += in1[k] * W1[k * HH + tid];
    hid[tid] = sigm(s);
  }
  __syncthreads();

  if (tid < 32) {
    float s = b2[tid];
    for (int k = 0; k < 128; ++k) s += hid[k] * W2[k * P1 + tid];
    out1[((size_t)b * NN + i) * P1 + tid] = sigm(s);
  }
}

// ---------------------------------------------------------------------------
// Arity-1 (fallback, full x2 scan) — used only if ws is too small.
// ---------------------------------------------------------------------------
__global__ __launch_bounds__(256) void k_arity1(
    const float* __restrict__ x0, const float* __restrict__ x1,
    const float* __restrict__ x2, const float* __restrict__ W1,
    const float* __restrict__ b1, const float* __restrict__ W2,
    const float* __restrict__ b2, float* __restrict__ out1) {
  __shared__ float rmx[8][32], rmn[8][32];
  __shared__ float in1[112];
  __shared__ float hid[128];

  const int tid = threadIdx.x;
  const int bid = blockIdx.x;  // 0..1023
  const int b = bid >> 9, i = bid & 511;
  const int p = tid & 31, jg = tid >> 5;

  const float* base = x2 + (((size_t)b * NN + i) * NN) * P2;
  float mx = 0.0f, mn = 1.0f;
  for (int j = jg; j < NN; j += 8) {
    const float v = base[(size_t)j * P2 + p];
    mx = fmaxf(mx, (j == i) ? 0.0f : v);
    mn = fminf(mn, (j == i) ? 1.0f : v);
  }
  rmx[jg][p] = mx;
  rmn[jg][p] = mn;
  __syncthreads();

  if (tid < 32) {
    float a = rmx[0][tid], c = rmn[0][tid];
#pragma unroll
    for (int g = 1; g < 8; ++g) {
      a = fmaxf(a, rmx[g][tid]);
      c = fminf(c, rmn[g][tid]);
    }
    in1[tid] = x1[((size_t)b * NN + i) * P1 + tid];
    in1[48 + tid] = a;
    in1[80 + tid] = c;
  } else if (tid < 48) {
    in1[tid] = x0[b * P0 + (tid - 32)];
  }
  __syncthreads();

  if (tid < 128) {
    float s = b1[tid];
    for (int k = 0; k < 112; ++k) s += in1[k] * W1[k * HH + tid];
    hid[tid] = sigm(s);
  }
  __syncthreads();

  if (tid < 32) {
    float s = b2[tid];
    for (int k = 0; k < 128; ++k) s += hid[k] * W2[k * P1 + tid];
    out1[((size_t)b * NN + i) * P1 + tid] = sigm(s);
  }
}

// ---------------------------------------------------------------------------
// Arity-0
// ---------------------------------------------------------------------------
__global__ __launch_bounds__(256) void k_arity0(
    const float* __restrict__ x0, const float* __restrict__ x1,
    const float* __restrict__ W1, const float* __restrict__ b1,
    const float* __restrict__ W2, const float* __restrict__ b2,
    float* __restrict__ out0) {
  __shared__ float rmx[8][32], rmn[8][32];
  __shared__ float in0[80];
  __shared__ float hid[128];

  const int tid = threadIdx.x;
  const int b = blockIdx.x;  // 0..1
  const int p = tid & 31, jg = tid >> 5;

  float mx = -1e30f, mn = 1e30f;
  for (int j = jg; j < NN; j += 8) {
    const float v = x1[((size_t)b * NN + j) * P1 + p];
    mx = fmaxf(mx, v);
    mn = fminf(mn, v);
  }
  rmx[jg][p] = mx;
  rmn[jg][p] = mn;
  __syncthreads();

  if (tid < 32) {
    float a = rmx[0][tid], c = rmn[0][tid];
#pragma unroll
    for (int g = 1; g < 8; ++g) {
      a = fmaxf(a, rmx[g][tid]);
      c = fminf(c, rmn[g][tid]);
    }
    in0[16 + tid] = a;
    in0[48 + tid] = c;
  } else if (tid < 48) {
    in0[tid - 32] = x0[b * P0 + (tid - 32)];
  }
  __syncthreads();

  if (tid < 128) {
    float s = b1[tid];
    for (int k = 0; k < 80; ++k) s += in0[k] * W1[k * HH + tid];
    hid[tid] = sigm(s);
  }
  __syncthreads();

  if (tid < 16) {
    float s = b2[tid];
    for (int k = 0; k < 128; ++k) s += hid[k] * W2[k * P0 + tid];
    out0[b * P0 + tid] = sigm(s);
  }
}

extern "C" void kernel_launch(void* const* d_in, const int* in_sizes, int n_in,
                              void* d_out, int out_size, void* d_ws, size_t ws_size,
                              hipStream_t stream) {
  const float* x0   = (const float*)d_in[0];
  const float* x1   = (const float*)d_in[1];
  const float* x2   = (const float*)d_in[2];
  const float* W1_0 = (const float*)d_in[3];
  const float* b1_0 = (const float*)d_in[4];
  const float* W2_0 = (const float*)d_in[5];
  const float* b2_0 = (const float*)d_in[6];
  const float* W1_1 = (const float*)d_in[7];
  const float* b1_1 = (const float*)d_in[8];
  const float* W2_1 = (const float*)d_in[9];
  const float* b2_1 = (const float*)d_in[10];
  const float* W1_2 = (const float*)d_in[11];
  const float* b1_2 = (const float*)d_in[12];
  const float* W2_2 = (const float*)d_in[13];
  const float* b2_2 = (const float*)d_in[14];

  float* out0 = (float*)d_out;
  float* out1 = out0 + (size_t)BB * P0;
  float* out2 = out1 + (size_t)BB * NN * P1;

  const bool use_ws = ws_size >= (size_t)BB * NN * 8 * 64 * sizeof(float);  // 2 MiB
  float* wsred = use_ws ? (float*)d_ws : nullptr;

  hipLaunchKernelGGL(k_arity2, dim3(2048), dim3(256), 0, stream,
                     x1, x2, W1_2, b1_2, W2_2, b2_2, out2, wsred);
  if (use_ws) {
    hipLaunchKernelGGL(k_arity1_fast, dim3(1024), dim3(128), 0, stream,
                       x0, x1, wsred, W1_1, b1_1, W2_1, b2_1, out1);
  } else {
    hipLaunchKernelGGL(k_arity1, dim3(1024), dim3(256), 0, stream,
                       x0, x1, x2, W1_1, b1_1, W2_1, b2_1, out1);
  }
  hipLaunchKernelGGL(k_arity0, dim3(2), dim3(256), 0, stream,
                     x0, x1, W1_0, b1_0, W2_0, b2_0, out0);
}